// Round 11
// baseline (314.728 us; speedup 1.0000x reference)
//
#include <hip/hip_runtime.h>

#define HDIM 1024
#define LSEQ 2048
#define NBATCH 4
#define NS 16
#define BL (NBATCH * LSEQ)   // 8192 rows
#define KDIM 1024
#define NX 1056              // 2*NS + HDIM
#define NXPAD 1152           // padded to 9*128
#define NCHUNK 64            // L chunks for the 3-phase scan
#define CLEN 32              // LSEQ / NCHUNK

typedef unsigned short u16;
typedef short short8 __attribute__((ext_vector_type(8)));
typedef float f32x4 __attribute__((ext_vector_type(4)));
typedef u16 u16x8 __attribute__((ext_vector_type(8)));
typedef u16 u16x2 __attribute__((ext_vector_type(2)));

__device__ __forceinline__ u16 f2bf(float f) {
  union { float f; unsigned u; } v; v.f = f;
  unsigned r = v.u + 0x7fffu + ((v.u >> 16) & 1u);   // round-to-nearest-even
  return (u16)(r >> 16);
}
__device__ __forceinline__ float bf2f(u16 b) {
  union { unsigned u; float f; } v; v.u = ((unsigned)b) << 16; return v.f;
}
__device__ __forceinline__ u16 f2h(float f) {          // fp32 -> fp16 (e5m10)
  union { _Float16 h; u16 u; } v; v.h = (_Float16)f; return v.u;
}
__device__ __forceinline__ float h2f(u16 h) {
  union { u16 u; _Float16 h; } v; v.u = h; return (float)v.h;
}

// async global->LDS, 16B per lane; LDS dest = wave-uniform base + lane*16
__device__ __forceinline__ void ld16(const void* g, void* l) {
  __builtin_amdgcn_global_load_lds(
      (const __attribute__((address_space(1))) unsigned int*)g,
      (__attribute__((address_space(3))) unsigned int*)l, 16, 0, 0);
}

// raw workgroup barrier (NO implicit vmcnt/lgkmcnt drain, unlike
// __syncthreads) with compiler-level memory fences.
__device__ __forceinline__ void rbar() {
  asm volatile("" ::: "memory");
  __builtin_amdgcn_s_barrier();
  asm volatile("" ::: "memory");
}

// ---------------- fused fp32 -> bf16 conversion (x, Wx->padded, Wout) ------
__global__ __launch_bounds__(256) void cvt_all_kernel(const float* __restrict__ x,
                                                      const float* __restrict__ Wx,
                                                      const float* __restrict__ Wout,
                                                      u16* __restrict__ x_bf,
                                                      u16* __restrict__ wx_bf,
                                                      u16* __restrict__ wo_bf) {
  const int blk = blockIdx.x;
  const float* in;
  u16* out;
  int i;
  bool zero = false;
  if (blk < 4096) {
    i = (blk * 256 + threadIdx.x) * 8;
    in = x; out = x_bf;
  } else if (blk < 4672) {
    i = ((blk - 4096) * 256 + threadIdx.x) * 8;
    in = Wx; out = wx_bf;
    zero = (i >> 10) >= NX;                 // pad rows 1056..1151
  } else {
    i = ((blk - 4672) * 256 + threadIdx.x) * 8;
    in = Wout; out = wo_bf;
  }
  u16x8 r;
  if (!zero) {
    float4 a = *(const float4*)(in + i);
    float4 b = *(const float4*)(in + i + 4);
    r[0] = f2bf(a.x); r[1] = f2bf(a.y); r[2] = f2bf(a.z); r[3] = f2bf(a.w);
    r[4] = f2bf(b.x); r[5] = f2bf(b.y); r[6] = f2bf(b.z); r[7] = f2bf(b.w);
  } else {
#pragma unroll
    for (int t = 0; t < 8; ++t) r[t] = 0;
  }
  *(u16x8*)(out + i) = r;
}

// ---------------- bf16 GEMM:  C(MxN) = A(MxK) * B(NxK)^T ----------------
// ROUND-18: settled at the r5 configuration = measured optimum of the
// full sweep (r0-r10):
//   r5: 128x128, BK=64, 32 MFMA/wave/step, 2 waves/SIMD, depth-2
//       counted-vmcnt (vmcnt(8), raw barriers), NO swizzle = 54.1 us best
//   r1 single-buf=65.4 | r2 dbuf-drain0=63.3 | r6 128x64=62.9 |
//   r7 barrier-free=95.1 | r8 256x128=68.6 | r10 +XCD-swizzle=57.5
//   (FETCH 3.3x: contiguous 72-tile chunks per XCD = whole-A working set
//   >> 4MB L2; the DEFAULT round-robin already gives each XCD every-8th
//   M-tile per N-panel = 2.25MB < L2. Do not re-add swizzle.)
template <int EPI>
__global__ __launch_bounds__(256) void gemm_bt(const u16* __restrict__ A,
                                               const u16* __restrict__ B,
                                               float* __restrict__ C,
                                               float* __restrict__ Bmo,
                                               float* __restrict__ Cmo,
                                               u16* __restrict__ Dlo,
                                               int N) {
  __shared__ __align__(16) u16 S[2][32 * 512];   // 64 KB double buffer
  const int tid = threadIdx.x, lane = tid & 63, w = tid >> 6;
  const int m0 = blockIdx.x * 128, n0 = blockIdx.y * 128;
  const int lr = lane & 15, lq = lane >> 4;
  const int wr = w >> 1, wc = w & 1;
  f32x4 acc[4][4] = {};

  // staging: wave w stages A chunks w*4..w*4+3 and B chunks w*4..w*4+3.
  // chunk ca: rows (ca>>1)*16..+16, k (ca&1)*32..+32 of the 128x64 tile.
  const u16* ga[4]; const u16* gb[4];
  int loA[4], loB[4];
#pragma unroll
  for (int c = 0; c < 4; ++c) {
    const int ca = w * 4 + c;                     // 0..15
    const int row = ((ca >> 1) << 4) + lr;
    const int col = ((ca & 1) << 5) + (lq << 3);
    ga[c] = A + (size_t)(m0 + row) * KDIM + col;
    gb[c] = B + (size_t)(n0 + row) * KDIM + col;
    loA[c] = ca * 512;
    loB[c] = (16 + ca) * 512;
  }

  auto stage = [&](int buf) {
    u16* base = &S[buf][0];
#pragma unroll
    for (int c = 0; c < 4; ++c) {
      ld16(ga[c], base + loA[c]);
      ld16(gb[c], base + loB[c]);
      ga[c] += 64; gb[c] += 64;
    }
  };

  auto compute = [&](int buf) {
    const u16* base = &S[buf][0];
#pragma unroll
    for (int kh = 0; kh < 2; ++kh) {
      short8 af[4], bfr[4];
#pragma unroll
      for (int i = 0; i < 4; ++i)
        af[i] = *(const short8*)(base + ((wr * 4 + i) * 2 + kh) * 512 + lane * 8);
#pragma unroll
      for (int j = 0; j < 4; ++j)
        bfr[j] = *(const short8*)(base + (16 + (wc * 4 + j) * 2 + kh) * 512 + lane * 8);
#pragma unroll
      for (int i = 0; i < 4; ++i)
#pragma unroll
        for (int j = 0; j < 4; ++j)
          acc[i][j] = __builtin_amdgcn_mfma_f32_16x16x32_bf16(af[i], bfr[j], acc[i][j], 0, 0, 0);
    }
  };

  // prologue: tiles 0 and 1 in flight (16 loads/wave), publish tile 0.
  stage(0);
  stage(1);
  asm volatile("s_waitcnt vmcnt(8)" ::: "memory");   // my tile-0 loads landed
  rbar();                                            // everyone's tile-0 landed
  int cur = 0;
  for (int kt = 0; kt < KDIM / 64 - 2; ++kt) {       // 14 steady-state steps
    compute(cur);
    rbar();                                          // buf[cur] free
    stage(cur);                                      // tile kt+2 -> buf[cur]
    asm volatile("s_waitcnt vmcnt(8)" ::: "memory"); // tile kt+1 landed (mine)
    rbar();                                          // tile kt+1 landed (all)
    cur ^= 1;
  }
  compute(cur);                                      // tile 14
  asm volatile("s_waitcnt vmcnt(0)" ::: "memory");   // tile 15 landed (mine)
  rbar();                                            // tile 15 landed (all)
  compute(cur ^ 1);                                  // tile 15

#pragma unroll
  for (int i = 0; i < 4; ++i) {
    const int gr0 = m0 + wr * 64 + i * 16 + lq * 4;
#pragma unroll
    for (int j = 0; j < 4; ++j) {
      const int gc = n0 + wc * 64 + j * 16 + lr;
      if (EPI == 0) {
        float* p = C + (size_t)gr0 * N + gc;
#pragma unroll
        for (int r = 0; r < 4; ++r) p[(size_t)r * N] = acc[i][j][r];
      } else {
        const int nt = gc >> 4;  // 16-col tile index
        if (nt == 0) {
#pragma unroll
          for (int r = 0; r < 4; ++r) Bmo[(gr0 + r) * NS + lr] = acc[i][j][r];
        } else if (nt == 1) {
#pragma unroll
          for (int r = 0; r < 4; ++r) Cmo[(gr0 + r) * NS + lr] = acc[i][j][r];
        } else if (nt < 66) {  // cols 32..1055 -> delta 0..1023, fp16
#pragma unroll
          for (int r = 0; r < 4; ++r) {
            float v = acc[i][j][r];
            float sp = fmaxf(v, 0.f) + __logf(1.f + __expf(-fabsf(v)));
            Dlo[(size_t)(gr0 + r) * HDIM + (gc - 2 * NS)] = f2h(sp);
          }
        }
      }
    }
  }
}

// ---------------- chunked selective scan, 3 phases ----------------
// r5 configuration (best measured): u16x2 2h/thread, NCHUNK=64, LDS-staged
// Bm/Cm (broadcast reads), barrier-free step loop, raw v_exp_f32.
// Scan probe history: load-width neutral (r3/r4), scalar-B/C neutral (r9),
// NCHUNK=32 regressed +13us (r10: 1 wave/SIMD too few). Non-GEMM noise
// band is +-8us — micro-tweaks are below measurement resolution.
template <int PHASE>
__global__ __launch_bounds__(256) void scan_phase(
    const u16* __restrict__ dlth, const u16* __restrict__ xb,
    const float* __restrict__ Bm, const float* __restrict__ Cm,
    const float* __restrict__ A_log, const float* __restrict__ Dvec,
    float* __restrict__ hbuf,      // [b][chunk][n][h]
    float* __restrict__ dts_out,   // [b][chunk][h]
    u16* __restrict__ yout) {
  __shared__ __align__(16) float sbt[CLEN][16];     // 2 KB
  __shared__ __align__(16) float sct[CLEN][16];     // 2 KB
  const int tid = threadIdx.x, lane = tid & 63, w = tid >> 6;
  const int b = blockIdx.x >> 6, c = blockIdx.x & 63;
  const int h = (blockIdx.y << 9) + tid * 2;        // 2 consecutive h per thread
  const size_t l0 = (size_t)b * LSEQ + (size_t)c * CLEN;

  if (w == 0) {
#pragma unroll
    for (int i = 0; i < 2; ++i)
      ld16(Bm + l0 * NS + i * 256 + lane * 4, (void*)(&sbt[0][0] + i * 256));
  } else if (w == 1 && PHASE == 3) {
#pragma unroll
    for (int i = 0; i < 2; ++i)
      ld16(Cm + l0 * NS + i * 256 + lane * 4, (void*)(&sct[0][0] + i * 256));
  }

  const u16* pd = dlth + l0 * HDIM + h;
  const u16* px = xb + l0 * HDIM + h;

  float Ae[16], hs[16][2];
#pragma unroll
  for (int n = 0; n < 16; ++n) Ae[n] = -expf(A_log[n]) * 1.44269504088896f;
  if (PHASE == 3 && c > 0) {
    const float* hp = hbuf + ((size_t)b * NCHUNK + (c - 1)) * NS * HDIM + h;
#pragma unroll
    for (int n = 0; n < 16; ++n) {
      const float2 t = *(const float2*)(hp + (size_t)n * HDIM);
      hs[n][0] = t.x; hs[n][1] = t.y;
    }
  } else {
#pragma unroll
    for (int n = 0; n < 16; ++n) { hs[n][0] = 0.f; hs[n][1] = 0.f; }
  }
  float Dh0 = 0.f, Dh1 = 0.f;
  if (PHASE == 3) { Dh0 = Dvec[h]; Dh1 = Dvec[h + 1]; }
  float dts0 = 0.f, dts1 = 0.f;

  u16x2 d0[8], x0[8], d1[8], x1[8];
  auto loadb = [&](int ks, u16x2* dd, u16x2* xx) {
#pragma unroll
    for (int j = 0; j < 8; ++j) {
      dd[j] = *(const u16x2*)(pd + (size_t)(ks * 8 + j) * HDIM);
      xx[j] = *(const u16x2*)(px + (size_t)(ks * 8 + j) * HDIM);
    }
  };
  auto compute = [&](int ks, const u16x2* dd, const u16x2* xx) {
#pragma unroll
    for (int s = 0; s < 8; ++s) {
      const int l = ks * 8 + s;
      const float dt0 = h2f(dd[s][0]), dt1 = h2f(dd[s][1]);
      const float xt0 = bf2f(xx[s][0]), xt1 = bf2f(xx[s][1]);
      const float dx0 = dt0 * xt0, dx1 = dt1 * xt1;
      if (PHASE == 1) { dts0 += dt0; dts1 += dt1; }
      float y0 = Dh0 * xt0, y1 = Dh1 * xt1;
      const f32x4* btp = (const f32x4*)&sbt[l][0];
      const f32x4* ctp = (const f32x4*)&sct[l][0];
#pragma unroll
      for (int q = 0; q < 4; ++q) {
        const f32x4 b4 = btp[q];               // broadcast read (same addr)
        f32x4 c4;
        if (PHASE == 3) c4 = ctp[q];
#pragma unroll
        for (int r = 0; r < 4; ++r) {
          const int n = q * 4 + r;
          const float dA0 = __builtin_amdgcn_exp2f(dt0 * Ae[n]);
          const float dA1 = __builtin_amdgcn_exp2f(dt1 * Ae[n]);
          hs[n][0] = fmaf(dA0, hs[n][0], b4[r] * dx0);
          hs[n][1] = fmaf(dA1, hs[n][1], b4[r] * dx1);
          if (PHASE == 3) {
            y0 = fmaf(hs[n][0], c4[r], y0);
            y1 = fmaf(hs[n][1], c4[r], y1);
          }
        }
      }
      if (PHASE == 3) {
        u16x2 yo; yo[0] = f2bf(y0); yo[1] = f2bf(y1);
        *(u16x2*)(yout + (l0 + l) * HDIM + h) = yo;
      }
    }
  };

  loadb(0, d0, x0);
  loadb(1, d1, x1);
  __syncthreads();                  // sbt/sct ready (only barrier in kernel)
  compute(0, d0, x0); loadb(2, d0, x0);
  compute(1, d1, x1); loadb(3, d1, x1);
  compute(2, d0, x0);
  compute(3, d1, x1);

  if (PHASE == 1) {
    float* hp = hbuf + ((size_t)b * NCHUNK + c) * NS * HDIM + h;
#pragma unroll
    for (int n = 0; n < 16; ++n)
      *(float2*)(hp + (size_t)n * HDIM) = float2{hs[n][0], hs[n][1]};
    *(float2*)(dts_out + ((size_t)b * NCHUNK + c) * HDIM + h) = float2{dts0, dts1};
  }
}

// PHASE 2: sequential prefix over chunks, in place (slot-shifted).
// ROUND-18: prefetch depth 4 (was 1) — the 63-step serial chain paid a
// dependent-load stall (~400cy L3) per step at depth 1; a 4-slot ring cuts
// the stall ~4x. Fully unrolled so ring indices are compile-time (rule
// #20: runtime-indexed register arrays go to scratch).
__global__ __launch_bounds__(256) void scan_combine(
    float* __restrict__ hbuf, const float* __restrict__ dts,
    const float* __restrict__ A_log) {
  const int id = blockIdx.x * 256 + threadIdx.x;   // 65536 = B*NS*H
  const int h = id & (HDIM - 1);
  const int n = (id >> 10) & (NS - 1);
  const int b = id >> 14;
  const float Ae = -expf(A_log[n]) * 1.44269504088896f;
  const size_t hstride = (size_t)NS * HDIM;
  float* hp = hbuf + ((size_t)b * NCHUNK * NS + n) * HDIM + h;
  const float* dp = dts + (size_t)b * NCHUNK * HDIM + h;
  float hs = 0.f;
  float nh[4], nd[4];
#pragma unroll
  for (int p = 0; p < 4; ++p) {                    // prefetch slots 0..3
    nh[p] = hp[(size_t)p * hstride];
    nd[p] = dp[(size_t)p * HDIM];
  }
#pragma unroll
  for (int c = 1; c < NCHUNK; ++c) {               // fully unrolled (63 iters)
    const int s = (c - 1) & 3;
    const float curh = nh[s], curd = nd[s];
    if (c + 3 < NCHUNK) {                          // prefetch slot c+3
      nh[s] = hp[(size_t)(c + 3) * hstride];
      nd[s] = dp[(size_t)(c + 3) * HDIM];
    }
    hs = fmaf(__builtin_amdgcn_exp2f(Ae * curd), hs, curh);
    hp[(size_t)(c - 1) * hstride] = hs;            // h_start[c] -> slot c-1
  }
}

// ---------------- launcher ----------------
extern "C" void kernel_launch(void* const* d_in, const int* in_sizes, int n_in,
                              void* d_out, int out_size, void* d_ws, size_t ws_size,
                              hipStream_t stream) {
  (void)in_sizes; (void)n_in; (void)out_size; (void)ws_size;
  const float* x     = (const float*)d_in[0];
  const float* Wx    = (const float*)d_in[1];
  const float* A_log = (const float*)d_in[2];
  const float* Dv    = (const float*)d_in[3];
  const float* Wout  = (const float*)d_in[4];
  float* out = (float*)d_out;

  char* ws = (char*)d_ws;
  u16*   x_bf  = (u16*)(ws);                       // 16,777,216 B (read by scans too)
  u16*   wx_bf = (u16*)(ws + 16777216);            //  2,359,296 B (alias: dts after gemm1)
  u16*   wo_bf = (u16*)(ws + 19136512);            //  2,097,152 B
  u16*   dlth  = (u16*)(ws + 21233664);            // 16,777,216 B (fp16 delta)
  float* hbuf  = (float*)(ws + 38010880);          // 16,777,216 B
  float* Bm    = (float*)(ws + 54788096);          //    524,288 B
  float* Cm    = (float*)(ws + 55312384);          //    524,288 B
  u16*   y_bf  = (u16*)(ws + 55836672);            // 16,777,216 B -> end 72,613,888
  float* dts   = (float*)wx_bf;                    // 1 MB needed, wx dead after gemm1

  cvt_all_kernel<<<5184, 256, 0, stream>>>(x, Wx, Wout, x_bf, wx_bf, wo_bf);

  dim3 g1(BL / 128, NXPAD / 128);  // 64 x 9 = 576 blocks
  gemm_bt<1><<<g1, 256, 0, stream>>>(x_bf, wx_bf, nullptr, Bm, Cm, dlth, NXPAD);

  dim3 gs(NBATCH * NCHUNK, HDIM / 512);  // 256 x 2 blocks (2 h per thread)
  scan_phase<1><<<gs, 256, 0, stream>>>(dlth, x_bf, Bm, Cm, A_log, Dv, hbuf, dts, nullptr);
  scan_combine<<<256, 256, 0, stream>>>(hbuf, dts, A_log);
  scan_phase<3><<<gs, 256, 0, stream>>>(dlth, x_bf, Bm, Cm, A_log, Dv, hbuf, dts, y_bf);

  dim3 g3(BL / 128, HDIM / 128);   // 64 x 8 = 512 blocks
  gemm_bt<0><<<g3, 256, 0, stream>>>(y_bf, wo_bf, out, nullptr, nullptr, nullptr, HDIM);
}

// Round 12
// 237.868 us; speedup vs baseline: 1.3231x; 1.3231x over previous
//
#include <hip/hip_runtime.h>

#define HDIM 1024
#define LSEQ 2048
#define NBATCH 4
#define NS 16
#define BL (NBATCH * LSEQ)   // 8192 rows
#define KDIM 1024
#define NX 1056              // 2*NS + HDIM
#define NXPAD 1152           // padded to 9*128
#define NCHUNK 64            // L chunks for the 3-phase scan
#define CLEN 32              // LSEQ / NCHUNK

typedef unsigned short u16;
typedef short short8 __attribute__((ext_vector_type(8)));
typedef float f32x4 __attribute__((ext_vector_type(4)));
typedef u16 u16x8 __attribute__((ext_vector_type(8)));
typedef u16 u16x2 __attribute__((ext_vector_type(2)));

__device__ __forceinline__ u16 f2bf(float f) {
  union { float f; unsigned u; } v; v.f = f;
  unsigned r = v.u + 0x7fffu + ((v.u >> 16) & 1u);   // round-to-nearest-even
  return (u16)(r >> 16);
}
__device__ __forceinline__ float bf2f(u16 b) {
  union { unsigned u; float f; } v; v.u = ((unsigned)b) << 16; return v.f;
}
__device__ __forceinline__ u16 f2h(float f) {          // fp32 -> fp16 (e5m10)
  union { _Float16 h; u16 u; } v; v.h = (_Float16)f; return v.u;
}
__device__ __forceinline__ float h2f(u16 h) {
  union { u16 u; _Float16 h; } v; v.u = h; return (float)v.h;
}

// async global->LDS, 16B per lane; LDS dest = wave-uniform base + lane*16
__device__ __forceinline__ void ld16(const void* g, void* l) {
  __builtin_amdgcn_global_load_lds(
      (const __attribute__((address_space(1))) unsigned int*)g,
      (__attribute__((address_space(3))) unsigned int*)l, 16, 0, 0);
}

// raw workgroup barrier (NO implicit vmcnt/lgkmcnt drain, unlike
// __syncthreads) with compiler-level memory fences.
__device__ __forceinline__ void rbar() {
  asm volatile("" ::: "memory");
  __builtin_amdgcn_s_barrier();
  asm volatile("" ::: "memory");
}

// ---------------- fused fp32 -> bf16 conversion (x, Wx->padded, Wout) ------
__global__ __launch_bounds__(256) void cvt_all_kernel(const float* __restrict__ x,
                                                      const float* __restrict__ Wx,
                                                      const float* __restrict__ Wout,
                                                      u16* __restrict__ x_bf,
                                                      u16* __restrict__ wx_bf,
                                                      u16* __restrict__ wo_bf) {
  const int blk = blockIdx.x;
  const float* in;
  u16* out;
  int i;
  bool zero = false;
  if (blk < 4096) {
    i = (blk * 256 + threadIdx.x) * 8;
    in = x; out = x_bf;
  } else if (blk < 4672) {
    i = ((blk - 4096) * 256 + threadIdx.x) * 8;
    in = Wx; out = wx_bf;
    zero = (i >> 10) >= NX;                 // pad rows 1056..1151
  } else {
    i = ((blk - 4672) * 256 + threadIdx.x) * 8;
    in = Wout; out = wo_bf;
  }
  u16x8 r;
  if (!zero) {
    float4 a = *(const float4*)(in + i);
    float4 b = *(const float4*)(in + i + 4);
    r[0] = f2bf(a.x); r[1] = f2bf(a.y); r[2] = f2bf(a.z); r[3] = f2bf(a.w);
    r[4] = f2bf(b.x); r[5] = f2bf(b.y); r[6] = f2bf(b.z); r[7] = f2bf(b.w);
  } else {
#pragma unroll
    for (int t = 0; t < 8; ++t) r[t] = 0;
  }
  *(u16x8*)(out + i) = r;
}

// ---------------- bf16 GEMM:  C(MxN) = A(MxK) * B(NxK)^T ----------------
// Settled r5 configuration = measured optimum of the full sweep (r0-r10):
//   r5: 128x128, BK=64, 32 MFMA/wave/step, 2 waves/SIMD, depth-2
//       counted-vmcnt (vmcnt(8), raw barriers), NO swizzle = 54.1 us best
//   r1 single-buf=65.4 | r2 dbuf-drain0=63.3 | r6 128x64=62.9 |
//   r7 barrier-free=95.1 | r8 256x128=68.6 | r10 +XCD-swizzle=57.5
//   (FETCH 3.3x: contiguous 72-tile chunks per XCD = whole-A working set
//   >> 4MB L2; the DEFAULT round-robin already gives each XCD every-8th
//   M-tile per N-panel = 2.25MB < L2. Do not re-add swizzle.)
// NOTE r11 measured this identical source at 79.5us with hbm_gbps 551 vs
// r9's 780 at identical FETCH/WRITE — uniform whole-run slowdown = clock/
// container anomaly, not code. Resubmitted unchanged for clean measurement.
template <int EPI>
__global__ __launch_bounds__(256) void gemm_bt(const u16* __restrict__ A,
                                               const u16* __restrict__ B,
                                               float* __restrict__ C,
                                               float* __restrict__ Bmo,
                                               float* __restrict__ Cmo,
                                               u16* __restrict__ Dlo,
                                               int N) {
  __shared__ __align__(16) u16 S[2][32 * 512];   // 64 KB double buffer
  const int tid = threadIdx.x, lane = tid & 63, w = tid >> 6;
  const int m0 = blockIdx.x * 128, n0 = blockIdx.y * 128;
  const int lr = lane & 15, lq = lane >> 4;
  const int wr = w >> 1, wc = w & 1;
  f32x4 acc[4][4] = {};

  // staging: wave w stages A chunks w*4..w*4+3 and B chunks w*4..w*4+3.
  // chunk ca: rows (ca>>1)*16..+16, k (ca&1)*32..+32 of the 128x64 tile.
  const u16* ga[4]; const u16* gb[4];
  int loA[4], loB[4];
#pragma unroll
  for (int c = 0; c < 4; ++c) {
    const int ca = w * 4 + c;                     // 0..15
    const int row = ((ca >> 1) << 4) + lr;
    const int col = ((ca & 1) << 5) + (lq << 3);
    ga[c] = A + (size_t)(m0 + row) * KDIM + col;
    gb[c] = B + (size_t)(n0 + row) * KDIM + col;
    loA[c] = ca * 512;
    loB[c] = (16 + ca) * 512;
  }

  auto stage = [&](int buf) {
    u16* base = &S[buf][0];
#pragma unroll
    for (int c = 0; c < 4; ++c) {
      ld16(ga[c], base + loA[c]);
      ld16(gb[c], base + loB[c]);
      ga[c] += 64; gb[c] += 64;
    }
  };

  auto compute = [&](int buf) {
    const u16* base = &S[buf][0];
#pragma unroll
    for (int kh = 0; kh < 2; ++kh) {
      short8 af[4], bfr[4];
#pragma unroll
      for (int i = 0; i < 4; ++i)
        af[i] = *(const short8*)(base + ((wr * 4 + i) * 2 + kh) * 512 + lane * 8);
#pragma unroll
      for (int j = 0; j < 4; ++j)
        bfr[j] = *(const short8*)(base + (16 + (wc * 4 + j) * 2 + kh) * 512 + lane * 8);
#pragma unroll
      for (int i = 0; i < 4; ++i)
#pragma unroll
        for (int j = 0; j < 4; ++j)
          acc[i][j] = __builtin_amdgcn_mfma_f32_16x16x32_bf16(af[i], bfr[j], acc[i][j], 0, 0, 0);
    }
  };

  // prologue: tiles 0 and 1 in flight (16 loads/wave), publish tile 0.
  stage(0);
  stage(1);
  asm volatile("s_waitcnt vmcnt(8)" ::: "memory");   // my tile-0 loads landed
  rbar();                                            // everyone's tile-0 landed
  int cur = 0;
  for (int kt = 0; kt < KDIM / 64 - 2; ++kt) {       // 14 steady-state steps
    compute(cur);
    rbar();                                          // buf[cur] free
    stage(cur);                                      // tile kt+2 -> buf[cur]
    asm volatile("s_waitcnt vmcnt(8)" ::: "memory"); // tile kt+1 landed (mine)
    rbar();                                          // tile kt+1 landed (all)
    cur ^= 1;
  }
  compute(cur);                                      // tile 14
  asm volatile("s_waitcnt vmcnt(0)" ::: "memory");   // tile 15 landed (mine)
  rbar();                                            // tile 15 landed (all)
  compute(cur ^ 1);                                  // tile 15

#pragma unroll
  for (int i = 0; i < 4; ++i) {
    const int gr0 = m0 + wr * 64 + i * 16 + lq * 4;
#pragma unroll
    for (int j = 0; j < 4; ++j) {
      const int gc = n0 + wc * 64 + j * 16 + lr;
      if (EPI == 0) {
        float* p = C + (size_t)gr0 * N + gc;
#pragma unroll
        for (int r = 0; r < 4; ++r) p[(size_t)r * N] = acc[i][j][r];
      } else {
        const int nt = gc >> 4;  // 16-col tile index
        if (nt == 0) {
#pragma unroll
          for (int r = 0; r < 4; ++r) Bmo[(gr0 + r) * NS + lr] = acc[i][j][r];
        } else if (nt == 1) {
#pragma unroll
          for (int r = 0; r < 4; ++r) Cmo[(gr0 + r) * NS + lr] = acc[i][j][r];
        } else if (nt < 66) {  // cols 32..1055 -> delta 0..1023, fp16
#pragma unroll
          for (int r = 0; r < 4; ++r) {
            float v = acc[i][j][r];
            float sp = fmaxf(v, 0.f) + __logf(1.f + __expf(-fabsf(v)));
            Dlo[(size_t)(gr0 + r) * HDIM + (gc - 2 * NS)] = f2h(sp);
          }
        }
      }
    }
  }
}

// ---------------- chunked selective scan, 3 phases ----------------
// r5 configuration (best measured): u16x2 2h/thread, NCHUNK=64, LDS-staged
// Bm/Cm (broadcast reads), barrier-free step loop, raw v_exp_f32.
// Scan probe history: load-width neutral (r3/r4), scalar-B/C neutral (r9),
// NCHUNK=32 regressed +13us (r10: 1 wave/SIMD too few). Non-GEMM noise
// band is +-8us — micro-tweaks are below measurement resolution.
template <int PHASE>
__global__ __launch_bounds__(256) void scan_phase(
    const u16* __restrict__ dlth, const u16* __restrict__ xb,
    const float* __restrict__ Bm, const float* __restrict__ Cm,
    const float* __restrict__ A_log, const float* __restrict__ Dvec,
    float* __restrict__ hbuf,      // [b][chunk][n][h]
    float* __restrict__ dts_out,   // [b][chunk][h]
    u16* __restrict__ yout) {
  __shared__ __align__(16) float sbt[CLEN][16];     // 2 KB
  __shared__ __align__(16) float sct[CLEN][16];     // 2 KB
  const int tid = threadIdx.x, lane = tid & 63, w = tid >> 6;
  const int b = blockIdx.x >> 6, c = blockIdx.x & 63;
  const int h = (blockIdx.y << 9) + tid * 2;        // 2 consecutive h per thread
  const size_t l0 = (size_t)b * LSEQ + (size_t)c * CLEN;

  if (w == 0) {
#pragma unroll
    for (int i = 0; i < 2; ++i)
      ld16(Bm + l0 * NS + i * 256 + lane * 4, (void*)(&sbt[0][0] + i * 256));
  } else if (w == 1 && PHASE == 3) {
#pragma unroll
    for (int i = 0; i < 2; ++i)
      ld16(Cm + l0 * NS + i * 256 + lane * 4, (void*)(&sct[0][0] + i * 256));
  }

  const u16* pd = dlth + l0 * HDIM + h;
  const u16* px = xb + l0 * HDIM + h;

  float Ae[16], hs[16][2];
#pragma unroll
  for (int n = 0; n < 16; ++n) Ae[n] = -expf(A_log[n]) * 1.44269504088896f;
  if (PHASE == 3 && c > 0) {
    const float* hp = hbuf + ((size_t)b * NCHUNK + (c - 1)) * NS * HDIM + h;
#pragma unroll
    for (int n = 0; n < 16; ++n) {
      const float2 t = *(const float2*)(hp + (size_t)n * HDIM);
      hs[n][0] = t.x; hs[n][1] = t.y;
    }
  } else {
#pragma unroll
    for (int n = 0; n < 16; ++n) { hs[n][0] = 0.f; hs[n][1] = 0.f; }
  }
  float Dh0 = 0.f, Dh1 = 0.f;
  if (PHASE == 3) { Dh0 = Dvec[h]; Dh1 = Dvec[h + 1]; }
  float dts0 = 0.f, dts1 = 0.f;

  u16x2 d0[8], x0[8], d1[8], x1[8];
  auto loadb = [&](int ks, u16x2* dd, u16x2* xx) {
#pragma unroll
    for (int j = 0; j < 8; ++j) {
      dd[j] = *(const u16x2*)(pd + (size_t)(ks * 8 + j) * HDIM);
      xx[j] = *(const u16x2*)(px + (size_t)(ks * 8 + j) * HDIM);
    }
  };
  auto compute = [&](int ks, const u16x2* dd, const u16x2* xx) {
#pragma unroll
    for (int s = 0; s < 8; ++s) {
      const int l = ks * 8 + s;
      const float dt0 = h2f(dd[s][0]), dt1 = h2f(dd[s][1]);
      const float xt0 = bf2f(xx[s][0]), xt1 = bf2f(xx[s][1]);
      const float dx0 = dt0 * xt0, dx1 = dt1 * xt1;
      if (PHASE == 1) { dts0 += dt0; dts1 += dt1; }
      float y0 = Dh0 * xt0, y1 = Dh1 * xt1;
      const f32x4* btp = (const f32x4*)&sbt[l][0];
      const f32x4* ctp = (const f32x4*)&sct[l][0];
#pragma unroll
      for (int q = 0; q < 4; ++q) {
        const f32x4 b4 = btp[q];               // broadcast read (same addr)
        f32x4 c4;
        if (PHASE == 3) c4 = ctp[q];
#pragma unroll
        for (int r = 0; r < 4; ++r) {
          const int n = q * 4 + r;
          const float dA0 = __builtin_amdgcn_exp2f(dt0 * Ae[n]);
          const float dA1 = __builtin_amdgcn_exp2f(dt1 * Ae[n]);
          hs[n][0] = fmaf(dA0, hs[n][0], b4[r] * dx0);
          hs[n][1] = fmaf(dA1, hs[n][1], b4[r] * dx1);
          if (PHASE == 3) {
            y0 = fmaf(hs[n][0], c4[r], y0);
            y1 = fmaf(hs[n][1], c4[r], y1);
          }
        }
      }
      if (PHASE == 3) {
        u16x2 yo; yo[0] = f2bf(y0); yo[1] = f2bf(y1);
        *(u16x2*)(yout + (l0 + l) * HDIM + h) = yo;
      }
    }
  };

  loadb(0, d0, x0);
  loadb(1, d1, x1);
  __syncthreads();                  // sbt/sct ready (only barrier in kernel)
  compute(0, d0, x0); loadb(2, d0, x0);
  compute(1, d1, x1); loadb(3, d1, x1);
  compute(2, d0, x0);
  compute(3, d1, x1);

  if (PHASE == 1) {
    float* hp = hbuf + ((size_t)b * NCHUNK + c) * NS * HDIM + h;
#pragma unroll
    for (int n = 0; n < 16; ++n)
      *(float2*)(hp + (size_t)n * HDIM) = float2{hs[n][0], hs[n][1]};
    *(float2*)(dts_out + ((size_t)b * NCHUNK + c) * HDIM + h) = float2{dts0, dts1};
  }
}

// PHASE 2: sequential prefix over chunks, in place (slot-shifted).
// Prefetch depth 4 — the 63-step serial chain paid a dependent-load stall
// (~400cy L3) per step at depth 1; a 4-slot ring cuts the stall ~4x.
// Fully unrolled so ring indices are compile-time (rule #20).
__global__ __launch_bounds__(256) void scan_combine(
    float* __restrict__ hbuf, const float* __restrict__ dts,
    const float* __restrict__ A_log) {
  const int id = blockIdx.x * 256 + threadIdx.x;   // 65536 = B*NS*H
  const int h = id & (HDIM - 1);
  const int n = (id >> 10) & (NS - 1);
  const int b = id >> 14;
  const float Ae = -expf(A_log[n]) * 1.44269504088896f;
  const size_t hstride = (size_t)NS * HDIM;
  float* hp = hbuf + ((size_t)b * NCHUNK * NS + n) * HDIM + h;
  const float* dp = dts + (size_t)b * NCHUNK * HDIM + h;
  float hs = 0.f;
  float nh[4], nd[4];
#pragma unroll
  for (int p = 0; p < 4; ++p) {                    // prefetch slots 0..3
    nh[p] = hp[(size_t)p * hstride];
    nd[p] = dp[(size_t)p * HDIM];
  }
#pragma unroll
  for (int c = 1; c < NCHUNK; ++c) {               // fully unrolled (63 iters)
    const int s = (c - 1) & 3;
    const float curh = nh[s], curd = nd[s];
    if (c + 3 < NCHUNK) {                          // prefetch slot c+3
      nh[s] = hp[(size_t)(c + 3) * hstride];
      nd[s] = dp[(size_t)(c + 3) * HDIM];
    }
    hs = fmaf(__builtin_amdgcn_exp2f(Ae * curd), hs, curh);
    hp[(size_t)(c - 1) * hstride] = hs;            // h_start[c] -> slot c-1
  }
}

// ---------------- launcher ----------------
extern "C" void kernel_launch(void* const* d_in, const int* in_sizes, int n_in,
                              void* d_out, int out_size, void* d_ws, size_t ws_size,
                              hipStream_t stream) {
  (void)in_sizes; (void)n_in; (void)out_size; (void)ws_size;
  const float* x     = (const float*)d_in[0];
  const float* Wx    = (const float*)d_in[1];
  const float* A_log = (const float*)d_in[2];
  const float* Dv    = (const float*)d_in[3];
  const float* Wout  = (const float*)d_in[4];
  float* out = (float*)d_out;

  char* ws = (char*)d_ws;
  u16*   x_bf  = (u16*)(ws);                       // 16,777,216 B (read by scans too)
  u16*   wx_bf = (u16*)(ws + 16777216);            //  2,359,296 B (alias: dts after gemm1)
  u16*   wo_bf = (u16*)(ws + 19136512);            //  2,097,152 B
  u16*   dlth  = (u16*)(ws + 21233664);            // 16,777,216 B (fp16 delta)
  float* hbuf  = (float*)(ws + 38010880);          // 16,777,216 B
  float* Bm    = (float*)(ws + 54788096);          //    524,288 B
  float* Cm    = (float*)(ws + 55312384);          //    524,288 B
  u16*   y_bf  = (u16*)(ws + 55836672);            // 16,777,216 B -> end 72,613,888
  float* dts   = (float*)wx_bf;                    // 1 MB needed, wx dead after gemm1

  cvt_all_kernel<<<5184, 256, 0, stream>>>(x, Wx, Wout, x_bf, wx_bf, wo_bf);

  dim3 g1(BL / 128, NXPAD / 128);  // 64 x 9 = 576 blocks
  gemm_bt<1><<<g1, 256, 0, stream>>>(x_bf, wx_bf, nullptr, Bm, Cm, dlth, NXPAD);

  dim3 gs(NBATCH * NCHUNK, HDIM / 512);  // 256 x 2 blocks (2 h per thread)
  scan_phase<1><<<gs, 256, 0, stream>>>(dlth, x_bf, Bm, Cm, A_log, Dv, hbuf, dts, nullptr);
  scan_combine<<<256, 256, 0, stream>>>(hbuf, dts, A_log);
  scan_phase<3><<<gs, 256, 0, stream>>>(dlth, x_bf, Bm, Cm, A_log, Dv, hbuf, dts, y_bf);

  dim3 g3(BL / 128, HDIM / 128);   // 64 x 8 = 512 blocks
  gemm_bt<0><<<g3, 256, 0, stream>>>(y_bf, wo_bf, out, nullptr, nullptr, nullptr, HDIM);
}

// Round 14
// 234.013 us; speedup vs baseline: 1.3449x; 1.0165x over previous
//
#include <hip/hip_runtime.h>

#define HDIM 1024
#define LSEQ 2048
#define NBATCH 4
#define NS 16
#define BL (NBATCH * LSEQ)   // 8192 rows
#define KDIM 1024
#define NX 1056              // 2*NS + HDIM
#define NXPAD 1152           // padded to 9*128
#define NCHUNK 64            // L chunks for the 3-phase scan
#define CLEN 32              // LSEQ / NCHUNK

typedef unsigned short u16;
typedef short short8 __attribute__((ext_vector_type(8)));
typedef float f32x4 __attribute__((ext_vector_type(4)));
typedef u16 u16x8 __attribute__((ext_vector_type(8)));
typedef u16 u16x2 __attribute__((ext_vector_type(2)));

__device__ __forceinline__ u16 f2bf(float f) {
  union { float f; unsigned u; } v; v.f = f;
  unsigned r = v.u + 0x7fffu + ((v.u >> 16) & 1u);   // round-to-nearest-even
  return (u16)(r >> 16);
}
__device__ __forceinline__ float bf2f(u16 b) {
  union { unsigned u; float f; } v; v.u = ((unsigned)b) << 16; return v.f;
}
__device__ __forceinline__ u16 f2h(float f) {          // fp32 -> fp16 (e5m10)
  union { _Float16 h; u16 u; } v; v.h = (_Float16)f; return v.u;
}
__device__ __forceinline__ float h2f(u16 h) {
  union { u16 u; _Float16 h; } v; v.u = h; return (float)v.h;
}

// async global->LDS, 16B per lane; LDS dest = wave-uniform base + lane*16
__device__ __forceinline__ void ld16(const void* g, void* l) {
  __builtin_amdgcn_global_load_lds(
      (const __attribute__((address_space(1))) unsigned int*)g,
      (__attribute__((address_space(3))) unsigned int*)l, 16, 0, 0);
}

// raw workgroup barrier (NO implicit vmcnt/lgkmcnt drain, unlike
// __syncthreads) with compiler-level memory fences.
__device__ __forceinline__ void rbar() {
  asm volatile("" ::: "memory");
  __builtin_amdgcn_s_barrier();
  asm volatile("" ::: "memory");
}

// ---------------- fused fp32 -> bf16 conversion (x, Wx->padded, Wout) ------
// ROUND-20: block 5184 additionally precomputes aebuf[n] = -exp(A_log[n])
// * log2e once, removing 16 guarded OCML expf calls PER THREAD from both
// scan phases and one from combine (they all re-derived the same 16 values).
// NOTE r13: fusing the 3 scan dispatches into one cooperative launch FAILED
// correctness (absmax 60.75) — grid.sync + threadfence did not provide the
// cross-XCD visibility that kernel boundaries do (Guideline 16). Scan stays
// as 3 separate dispatches; do not re-attempt grid-sync fusion headlessly.
__global__ __launch_bounds__(256) void cvt_all_kernel(const float* __restrict__ x,
                                                      const float* __restrict__ Wx,
                                                      const float* __restrict__ Wout,
                                                      const float* __restrict__ A_log,
                                                      u16* __restrict__ x_bf,
                                                      u16* __restrict__ wx_bf,
                                                      u16* __restrict__ wo_bf,
                                                      float* __restrict__ aebuf) {
  const int blk = blockIdx.x;
  if (blk == 5184) {
    if (threadIdx.x < 16)
      aebuf[threadIdx.x] = -expf(A_log[threadIdx.x]) * 1.44269504088896f;
    return;
  }
  const float* in;
  u16* out;
  int i;
  bool zero = false;
  if (blk < 4096) {
    i = (blk * 256 + threadIdx.x) * 8;
    in = x; out = x_bf;
  } else if (blk < 4672) {
    i = ((blk - 4096) * 256 + threadIdx.x) * 8;
    in = Wx; out = wx_bf;
    zero = (i >> 10) >= NX;                 // pad rows 1056..1151
  } else {
    i = ((blk - 4672) * 256 + threadIdx.x) * 8;
    in = Wout; out = wo_bf;
  }
  u16x8 r;
  if (!zero) {
    float4 a = *(const float4*)(in + i);
    float4 b = *(const float4*)(in + i + 4);
    r[0] = f2bf(a.x); r[1] = f2bf(a.y); r[2] = f2bf(a.z); r[3] = f2bf(a.w);
    r[4] = f2bf(b.x); r[5] = f2bf(b.y); r[6] = f2bf(b.z); r[7] = f2bf(b.w);
  } else {
#pragma unroll
    for (int t = 0; t < 8; ++t) r[t] = 0;
  }
  *(u16x8*)(out + i) = r;
}

// ---------------- bf16 GEMM:  C(MxN) = A(MxK) * B(NxK)^T ----------------
// Settled r5 configuration = measured optimum of the full sweep (r0-r10):
//   128x128, BK=64, 32 MFMA/wave/step, 2 waves/SIMD, depth-2 counted-vmcnt
//   (vmcnt(8), raw barriers), NO swizzle = 54.1-54.3 us (r5/r9/r12).
//   r10's XCD swizzle: FETCH 3.3x, regression — default round-robin already
//   gives each XCD every-8th M-tile per N-panel (2.25MB < 4MB L2).
template <int EPI>
__global__ __launch_bounds__(256) void gemm_bt(const u16* __restrict__ A,
                                               const u16* __restrict__ B,
                                               float* __restrict__ C,
                                               float* __restrict__ Bmo,
                                               float* __restrict__ Cmo,
                                               u16* __restrict__ Dlo,
                                               int N) {
  __shared__ __align__(16) u16 S[2][32 * 512];   // 64 KB double buffer
  const int tid = threadIdx.x, lane = tid & 63, w = tid >> 6;
  const int m0 = blockIdx.x * 128, n0 = blockIdx.y * 128;
  const int lr = lane & 15, lq = lane >> 4;
  const int wr = w >> 1, wc = w & 1;
  f32x4 acc[4][4] = {};

  const u16* ga[4]; const u16* gb[4];
  int loA[4], loB[4];
#pragma unroll
  for (int c = 0; c < 4; ++c) {
    const int ca = w * 4 + c;                     // 0..15
    const int row = ((ca >> 1) << 4) + lr;
    const int col = ((ca & 1) << 5) + (lq << 3);
    ga[c] = A + (size_t)(m0 + row) * KDIM + col;
    gb[c] = B + (size_t)(n0 + row) * KDIM + col;
    loA[c] = ca * 512;
    loB[c] = (16 + ca) * 512;
  }

  auto stage = [&](int buf) {
    u16* base = &S[buf][0];
#pragma unroll
    for (int c = 0; c < 4; ++c) {
      ld16(ga[c], base + loA[c]);
      ld16(gb[c], base + loB[c]);
      ga[c] += 64; gb[c] += 64;
    }
  };

  auto compute = [&](int buf) {
    const u16* base = &S[buf][0];
#pragma unroll
    for (int kh = 0; kh < 2; ++kh) {
      short8 af[4], bfr[4];
#pragma unroll
      for (int i = 0; i < 4; ++i)
        af[i] = *(const short8*)(base + ((wr * 4 + i) * 2 + kh) * 512 + lane * 8);
#pragma unroll
      for (int j = 0; j < 4; ++j)
        bfr[j] = *(const short8*)(base + (16 + (wc * 4 + j) * 2 + kh) * 512 + lane * 8);
#pragma unroll
      for (int i = 0; i < 4; ++i)
#pragma unroll
        for (int j = 0; j < 4; ++j)
          acc[i][j] = __builtin_amdgcn_mfma_f32_16x16x32_bf16(af[i], bfr[j], acc[i][j], 0, 0, 0);
    }
  };

  stage(0);
  stage(1);
  asm volatile("s_waitcnt vmcnt(8)" ::: "memory");   // my tile-0 loads landed
  rbar();                                            // everyone's tile-0 landed
  int cur = 0;
  for (int kt = 0; kt < KDIM / 64 - 2; ++kt) {       // 14 steady-state steps
    compute(cur);
    rbar();                                          // buf[cur] free
    stage(cur);                                      // tile kt+2 -> buf[cur]
    asm volatile("s_waitcnt vmcnt(8)" ::: "memory"); // tile kt+1 landed (mine)
    rbar();                                          // tile kt+1 landed (all)
    cur ^= 1;
  }
  compute(cur);                                      // tile 14
  asm volatile("s_waitcnt vmcnt(0)" ::: "memory");   // tile 15 landed (mine)
  rbar();                                            // tile 15 landed (all)
  compute(cur ^ 1);                                  // tile 15

#pragma unroll
  for (int i = 0; i < 4; ++i) {
    const int gr0 = m0 + wr * 64 + i * 16 + lq * 4;
#pragma unroll
    for (int j = 0; j < 4; ++j) {
      const int gc = n0 + wc * 64 + j * 16 + lr;
      if (EPI == 0) {
        float* p = C + (size_t)gr0 * N + gc;
#pragma unroll
        for (int r = 0; r < 4; ++r) p[(size_t)r * N] = acc[i][j][r];
      } else {
        const int nt = gc >> 4;  // 16-col tile index
        if (nt == 0) {
#pragma unroll
          for (int r = 0; r < 4; ++r) Bmo[(gr0 + r) * NS + lr] = acc[i][j][r];
        } else if (nt == 1) {
#pragma unroll
          for (int r = 0; r < 4; ++r) Cmo[(gr0 + r) * NS + lr] = acc[i][j][r];
        } else if (nt < 66) {  // cols 32..1055 -> delta 0..1023, fp16
#pragma unroll
          for (int r = 0; r < 4; ++r) {
            float v = acc[i][j][r];
            float sp = fmaxf(v, 0.f) + __logf(1.f + __expf(-fabsf(v)));
            Dlo[(size_t)(gr0 + r) * HDIM + (gc - 2 * NS)] = f2h(sp);
          }
        }
      }
    }
  }
}

// ---------------- chunked selective scan, 3 phases ----------------
// r5 configuration (best measured): u16x2 2h/thread, NCHUNK=64, LDS-staged
// Bm/Cm (broadcast reads), barrier-free step loop, raw v_exp_f32.
// ROUND-20: Ae comes from aebuf (precomputed in cvt) — wave-uniform scalar
// loads instead of 16 guarded OCML expf per thread.
// Scan probe history: load-width neutral (r3/r4), scalar-B/C neutral (r9),
// NCHUNK=32 regressed +13us (r10). Non-GEMM noise band is +-8us.
template <int PHASE>
__global__ __launch_bounds__(256) void scan_phase(
    const u16* __restrict__ dlth, const u16* __restrict__ xb,
    const float* __restrict__ Bm, const float* __restrict__ Cm,
    const float* __restrict__ aebuf, const float* __restrict__ Dvec,
    float* __restrict__ hbuf,      // [b][chunk][n][h]
    float* __restrict__ dts_out,   // [b][chunk][h]
    u16* __restrict__ yout) {
  __shared__ __align__(16) float sbt[CLEN][16];     // 2 KB
  __shared__ __align__(16) float sct[CLEN][16];     // 2 KB
  const int tid = threadIdx.x, lane = tid & 63, w = tid >> 6;
  const int b = blockIdx.x >> 6, c = blockIdx.x & 63;
  const int h = (blockIdx.y << 9) + tid * 2;        // 2 consecutive h per thread
  const size_t l0 = (size_t)b * LSEQ + (size_t)c * CLEN;

  if (w == 0) {
#pragma unroll
    for (int i = 0; i < 2; ++i)
      ld16(Bm + l0 * NS + i * 256 + lane * 4, (void*)(&sbt[0][0] + i * 256));
  } else if (w == 1 && PHASE == 3) {
#pragma unroll
    for (int i = 0; i < 2; ++i)
      ld16(Cm + l0 * NS + i * 256 + lane * 4, (void*)(&sct[0][0] + i * 256));
  }

  const u16* pd = dlth + l0 * HDIM + h;
  const u16* px = xb + l0 * HDIM + h;

  float Ae[16], hs[16][2];
#pragma unroll
  for (int n = 0; n < 16; ++n) Ae[n] = aebuf[n];    // uniform addr -> s_load
  if (PHASE == 3 && c > 0) {
    const float* hp = hbuf + ((size_t)b * NCHUNK + (c - 1)) * NS * HDIM + h;
#pragma unroll
    for (int n = 0; n < 16; ++n) {
      const float2 t = *(const float2*)(hp + (size_t)n * HDIM);
      hs[n][0] = t.x; hs[n][1] = t.y;
    }
  } else {
#pragma unroll
    for (int n = 0; n < 16; ++n) { hs[n][0] = 0.f; hs[n][1] = 0.f; }
  }
  float Dh0 = 0.f, Dh1 = 0.f;
  if (PHASE == 3) { Dh0 = Dvec[h]; Dh1 = Dvec[h + 1]; }
  float dts0 = 0.f, dts1 = 0.f;

  u16x2 d0[8], x0[8], d1[8], x1[8];
  auto loadb = [&](int ks, u16x2* dd, u16x2* xx) {
#pragma unroll
    for (int j = 0; j < 8; ++j) {
      dd[j] = *(const u16x2*)(pd + (size_t)(ks * 8 + j) * HDIM);
      xx[j] = *(const u16x2*)(px + (size_t)(ks * 8 + j) * HDIM);
    }
  };
  auto compute = [&](int ks, const u16x2* dd, const u16x2* xx) {
#pragma unroll
    for (int s = 0; s < 8; ++s) {
      const int l = ks * 8 + s;
      const float dt0 = h2f(dd[s][0]), dt1 = h2f(dd[s][1]);
      const float xt0 = bf2f(xx[s][0]), xt1 = bf2f(xx[s][1]);
      const float dx0 = dt0 * xt0, dx1 = dt1 * xt1;
      if (PHASE == 1) { dts0 += dt0; dts1 += dt1; }
      float y0 = Dh0 * xt0, y1 = Dh1 * xt1;
      const f32x4* btp = (const f32x4*)&sbt[l][0];
      const f32x4* ctp = (const f32x4*)&sct[l][0];
#pragma unroll
      for (int q = 0; q < 4; ++q) {
        const f32x4 b4 = btp[q];               // broadcast read (same addr)
        f32x4 c4;
        if (PHASE == 3) c4 = ctp[q];
#pragma unroll
        for (int r = 0; r < 4; ++r) {
          const int n = q * 4 + r;
          const float dA0 = __builtin_amdgcn_exp2f(dt0 * Ae[n]);
          const float dA1 = __builtin_amdgcn_exp2f(dt1 * Ae[n]);
          hs[n][0] = fmaf(dA0, hs[n][0], b4[r] * dx0);
          hs[n][1] = fmaf(dA1, hs[n][1], b4[r] * dx1);
          if (PHASE == 3) {
            y0 = fmaf(hs[n][0], c4[r], y0);
            y1 = fmaf(hs[n][1], c4[r], y1);
          }
        }
      }
      if (PHASE == 3) {
        u16x2 yo; yo[0] = f2bf(y0); yo[1] = f2bf(y1);
        *(u16x2*)(yout + (l0 + l) * HDIM + h) = yo;
      }
    }
  };

  loadb(0, d0, x0);
  loadb(1, d1, x1);
  __syncthreads();                  // sbt/sct ready (only barrier in kernel)
  compute(0, d0, x0); loadb(2, d0, x0);
  compute(1, d1, x1); loadb(3, d1, x1);
  compute(2, d0, x0);
  compute(3, d1, x1);

  if (PHASE == 1) {
    float* hp = hbuf + ((size_t)b * NCHUNK + c) * NS * HDIM + h;
#pragma unroll
    for (int n = 0; n < 16; ++n)
      *(float2*)(hp + (size_t)n * HDIM) = float2{hs[n][0], hs[n][1]};
    *(float2*)(dts_out + ((size_t)b * NCHUNK + c) * HDIM + h) = float2{dts0, dts1};
  }
}

// PHASE 2: sequential prefix over chunks, in place (slot-shifted).
// Prefetch depth 4 — the 63-step serial chain paid a dependent-load stall
// (~400cy L3) per step at depth 1; a 4-slot ring cuts the stall ~4x.
// Fully unrolled so ring indices are compile-time (rule #20).
__global__ __launch_bounds__(256) void scan_combine(
    float* __restrict__ hbuf, const float* __restrict__ dts,
    const float* __restrict__ aebuf) {
  const int id = blockIdx.x * 256 + threadIdx.x;   // 65536 = B*NS*H
  const int h = id & (HDIM - 1);
  const int n = (id >> 10) & (NS - 1);
  const int b = id >> 14;
  const float Ae = aebuf[n];
  const size_t hstride = (size_t)NS * HDIM;
  float* hp = hbuf + ((size_t)b * NCHUNK * NS + n) * HDIM + h;
  const float* dp = dts + (size_t)b * NCHUNK * HDIM + h;
  float hs = 0.f;
  float nh[4], nd[4];
#pragma unroll
  for (int p = 0; p < 4; ++p) {                    // prefetch slots 0..3
    nh[p] = hp[(size_t)p * hstride];
    nd[p] = dp[(size_t)p * HDIM];
  }
#pragma unroll
  for (int c = 1; c < NCHUNK; ++c) {               // fully unrolled (63 iters)
    const int s = (c - 1) & 3;
    const float curh = nh[s], curd = nd[s];
    if (c + 3 < NCHUNK) {                          // prefetch slot c+3
      nh[s] = hp[(size_t)(c + 3) * hstride];
      nd[s] = dp[(size_t)(c + 3) * HDIM];
    }
    hs = fmaf(__builtin_amdgcn_exp2f(Ae * curd), hs, curh);
    hp[(size_t)(c - 1) * hstride] = hs;            // h_start[c] -> slot c-1
  }
}

// ---------------- launcher ----------------
extern "C" void kernel_launch(void* const* d_in, const int* in_sizes, int n_in,
                              void* d_out, int out_size, void* d_ws, size_t ws_size,
                              hipStream_t stream) {
  (void)in_sizes; (void)n_in; (void)out_size; (void)ws_size;
  const float* x     = (const float*)d_in[0];
  const float* Wx    = (const float*)d_in[1];
  const float* A_log = (const float*)d_in[2];
  const float* Dv    = (const float*)d_in[3];
  const float* Wout  = (const float*)d_in[4];
  float* out = (float*)d_out;

  char* ws = (char*)d_ws;
  u16*   x_bf  = (u16*)(ws);                       // 16,777,216 B (read by scans too)
  u16*   wx_bf = (u16*)(ws + 16777216);            //  2,359,296 B (alias: dts after gemm1)
  u16*   wo_bf = (u16*)(ws + 19136512);            //  2,097,152 B
  u16*   dlth  = (u16*)(ws + 21233664);            // 16,777,216 B (fp16 delta)
  float* hbuf  = (float*)(ws + 38010880);          // 16,777,216 B
  float* Bm    = (float*)(ws + 54788096);          //    524,288 B
  float* Cm    = (float*)(ws + 55312384);          //    524,288 B
  u16*   y_bf  = (u16*)(ws + 55836672);            // 16,777,216 B
  float* aebuf = (float*)(ws + 72613888);          //         64 B -> end 72,613,952
  float* dts   = (float*)wx_bf;                    // 1 MB needed, wx dead after gemm1

  cvt_all_kernel<<<5185, 256, 0, stream>>>(x, Wx, Wout, A_log, x_bf, wx_bf, wo_bf, aebuf);

  dim3 g1(BL / 128, NXPAD / 128);  // 64 x 9 = 576 blocks
  gemm_bt<1><<<g1, 256, 0, stream>>>(x_bf, wx_bf, nullptr, Bm, Cm, dlth, NXPAD);

  dim3 gs(NBATCH * NCHUNK, HDIM / 512);  // 256 x 2 blocks (2 h per thread)
  scan_phase<1><<<gs, 256, 0, stream>>>(dlth, x_bf, Bm, Cm, aebuf, Dv, hbuf, dts, nullptr);
  scan_combine<<<256, 256, 0, stream>>>(hbuf, dts, aebuf);
  scan_phase<3><<<gs, 256, 0, stream>>>(dlth, x_bf, Bm, Cm, aebuf, Dv, hbuf, dts, y_bf);

  dim3 g3(BL / 128, HDIM / 128);   // 64 x 8 = 512 blocks
  gemm_bt<0><<<g3, 256, 0, stream>>>(y_bf, wo_bf, out, nullptr, nullptr, nullptr, HDIM);
}